// Round 4
// baseline (33.088 us; speedup 1.0000x reference)
//
#include <hip/hip_runtime.h>
#include <hip/hip_fp16.h>

#define NROWS 16384
#define NG 100
#define NC 10
#define NH 32
#define NS 10
#define GPC 10
#define SLOPE 0.2f
#define BN_EPS 1e-5f

#define EPADH 36           // halfs per LDS emb row (72B stride -> rows spread across banks)
#define RPB 16             // rows per main block
#define BLOCK_A 256        // 16 rows * 16 lanes/row

// d_ws layout (bytes)
#define WS_SUMS 0          // 8 stripes * 64 f32 = 2048 B  ([k*64+s]=sum, [k*64+32+s]=sumsq)
#define WS_EL   2048       // 300 f32 e-table
#define WS_WT   4096       // 320 f32 transposed W
#define WS_XP   8192       // 16384 rows * 8 u32 packed trits = 512 KiB
#define WS_NEED (8192 + NROWS * 8 * 4)

// ---------------- prep: pack x (2 bits/trit, 16 trits/u32) + global e-table + W^T ----------------
__global__ __launch_bounds__(256) void gga_prep(
    const int* __restrict__ x, const float* __restrict__ emb,
    const float* __restrict__ gene_att, const float* __restrict__ W,
    unsigned* __restrict__ xp, float* __restrict__ eLg, float* __restrict__ WTg)
{
    const int t = threadIdx.x;
    const int row = blockIdx.x * 32 + (t >> 3);
    const int l = t & 7;                     // word index within row
    unsigned w = 0u;
    if (l < 7) {
        const int4* p = reinterpret_cast<const int4*>(x + row * NG + l * 16);
        const int nvec = (l < 6) ? 4 : 1;    // word 6 holds trits 96..99 only
#pragma unroll
        for (int i = 0; i < 4; ++i) {
            if (i < nvec) {
                int4 v = p[i];
                w |= ((unsigned)v.x & 3u) << (i * 8 + 0);
                w |= ((unsigned)v.y & 3u) << (i * 8 + 2);
                w |= ((unsigned)v.z & 3u) << (i * 8 + 4);
                w |= ((unsigned)v.w & 3u) << (i * 8 + 6);
            }
        }
    }
    xp[row * 8 + l] = w;

    if (blockIdx.x == 0) {
        // e-table: exp(leaky(dot(gene_att[g/10], emb[g,x,:]))) * mask, full f32
        for (int i = t; i < 300; i += 256) {
            const int g = i / 3;
            const float* ga = gene_att + (g / GPC) * NH;
            const float* e = emb + i * NH;
            float s = 0.f;
#pragma unroll
            for (int k = 0; k < NH; ++k) s = fmaf(ga[k], e[k], s);
            const float lk = s > 0.f ? s : SLOPE * s;
            eLg[i] = (s != 0.f) ? __expf(lk) : 0.f;
        }
    } else if (blockIdx.x == 1) {
        for (int i = t; i < NH * NS; i += 256) {
            const int s = i >> 5, h = i & 31;
            WTg[i] = W[h * NS + s];          // WT[s][h]
        }
    }
}

// ---------------- main ----------------
template<bool PRE>
__global__ __launch_bounds__(BLOCK_A, 4) void gga_main(
    const int* __restrict__ x, const unsigned* __restrict__ xp,
    const float* __restrict__ emb, const float* __restrict__ gene_att,
    const float* __restrict__ chrom_att, const float* __restrict__ W,
    const float* __restrict__ b, const float* __restrict__ eLg,
    const float* __restrict__ WTg,
    float* __restrict__ y, float* __restrict__ sums)
{
    __shared__ __half embL[300 * EPADH];   // 21.6 KB
    __shared__ float eL[300];
    __shared__ float WTL[NS * NH];
    __shared__ float bL[NS];
    __shared__ float sAcc[2 * NS];

    const int t = threadIdx.x;

    // stage emb f32 -> f16 LDS (coalesced float4 reads, 8B LDS stores)
    for (int i = t; i < 2400; i += BLOCK_A) {
        float4 v = reinterpret_cast<const float4*>(emb)[i];
        int f = i << 2;
        int row = f >> 5, h = f & 31;
        __half2 lo = __floats2half2_rn(v.x, v.y);
        __half2 hi = __floats2half2_rn(v.z, v.w);
        uint2 u;
        u.x = __builtin_bit_cast(unsigned, lo);
        u.y = __builtin_bit_cast(unsigned, hi);
        *reinterpret_cast<uint2*>(&embL[row * EPADH + h]) = u;
    }
    if (PRE) {
        for (int i = t; i < 300; i += BLOCK_A) eL[i] = eLg[i];
        for (int i = t; i < NH * NS; i += BLOCK_A) WTL[i] = WTg[i];
    } else {
        for (int i = t; i < NH * NS; i += BLOCK_A) {
            int s = i >> 5, h = i & 31;
            WTL[i] = W[h * NS + s];
        }
    }
    if (t < NS) bL[t] = b[t];
    if (t < 2 * NS) sAcc[t] = 0.f;
    __syncthreads();
    if (!PRE) {   // fallback: e-table from f16 LDS
        for (int i = t; i < 300; i += BLOCK_A) {
            const int g = i / 3;
            const float* ga = gene_att + (g / GPC) * NH;
            float s = 0.f;
#pragma unroll
            for (int k = 0; k < NH; ++k) s = fmaf(ga[k], __half2float(embL[i * EPADH + k]), s);
            const float lk = s > 0.f ? s : SLOPE * s;
            eL[i] = (s != 0.f) ? __expf(lk) : 0.f;
        }
        __syncthreads();
    }

    const int lr = t >> 4;          // local row 0..15
    const int o = t & 15;           // owns h components 2o, 2o+1
    const int n = blockIdx.x * RPB + lr;

    const float2 ca = reinterpret_cast<const float2*>(chrom_att)[o];

    unsigned pk[8];
    if (PRE) {
        const int4* xr = reinterpret_cast<const int4*>(xp + n * 8);
        int4 a = xr[0], b2 = xr[1];
        pk[0] = (unsigned)a.x;  pk[1] = (unsigned)a.y;
        pk[2] = (unsigned)a.z;  pk[3] = (unsigned)a.w;
        pk[4] = (unsigned)b2.x; pk[5] = (unsigned)b2.y;
        pk[6] = (unsigned)b2.z; pk[7] = (unsigned)b2.w;
    } else {
#pragma unroll
        for (int i = 0; i < 8; ++i) pk[i] = 0u;
        const int4* xr = reinterpret_cast<const int4*>(x + n * NG);
#pragma unroll
        for (int i = 0; i < 25; ++i) {
            int4 v = xr[i];
            const int g0 = i * 4;
            pk[(g0 + 0) >> 4] |= ((unsigned)v.x & 3u) << (((g0 + 0) & 15) * 2);
            pk[(g0 + 1) >> 4] |= ((unsigned)v.y & 3u) << (((g0 + 1) & 15) * 2);
            pk[(g0 + 2) >> 4] |= ((unsigned)v.z & 3u) << (((g0 + 2) & 15) * 2);
            pk[(g0 + 3) >> 4] |= ((unsigned)v.w & 3u) << (((g0 + 3) & 15) * 2);
        }
    }

    float2 num = {0.f, 0.f};
    float den = 0.f;

#pragma unroll
    for (int c = 0; c < NC; ++c) {
        float e[GPC];
        float2 hf[GPC];
#pragma unroll
        for (int gp = 0; gp < GPC; ++gp) {
            const int g = c * GPC + gp;
            const unsigned xg = (pk[g >> 4] >> ((g & 15) * 2)) & 3u;
            const int r3 = g * 3 + (int)xg;
            e[gp] = eL[r3];                                   // broadcast-friendly
            __half2 hh = *reinterpret_cast<const __half2*>(&embL[r3 * EPADH + o * 2]);
            hf[gp] = __half22float2(hh);
        }
        float suma = 0.f;
#pragma unroll
        for (int gp = 0; gp < GPC; ++gp) suma += e[gp];
        const float inv = 1.f / fmaxf(suma, 1e-10f);

        float2 ch = {0.f, 0.f};
#pragma unroll
        for (int gp = 0; gp < GPC; ++gp) {
            ch.x = fmaf(e[gp], hf[gp].x, ch.x);
            ch.y = fmaf(e[gp], hf[gp].y, ch.y);
        }
        ch.x = fmaxf(ch.x, 0.f);   // ReLU commutes with the positive 1/suma scale
        ch.y = fmaxf(ch.y, 0.f);

        float pc = ch.x * ca.x + ch.y * ca.y;
        pc += __shfl_xor(pc, 1);
        pc += __shfl_xor(pc, 2);
        pc += __shfl_xor(pc, 4);
        pc += __shfl_xor(pc, 8);
        pc *= inv;                                            // catt[n][c]
        const float lc = pc > 0.f ? pc : SLOPE * pc;
        const float ec = __expf(lc);
        const float w = ec * inv;

        num.x = fmaf(w, ch.x, num.x);
        num.y = fmaf(w, ch.y, num.y);
        den += ec;
    }

    const float invd = 1.f / den;
    const float g0 = fmaxf(num.x * invd, 0.f);
    const float g1 = fmaxf(num.y * invd, 0.f);

    float ys[NS];
#pragma unroll
    for (int s = 0; s < NS; ++s) {
        const float2 wv = *reinterpret_cast<const float2*>(&WTL[s * NH + o * 2]);
        float p = g0 * wv.x + g1 * wv.y;
        p += __shfl_xor(p, 1);
        p += __shfl_xor(p, 2);
        p += __shfl_xor(p, 4);
        p += __shfl_xor(p, 8);
        ys[s] = p + bL[s];
    }

    if (o == 0) {
#pragma unroll
        for (int s = 0; s < NS; ++s) y[n * NS + s] = ys[s];
    }

    // BN partials: ys[s] is uniform across the 16 o-lanes of a row; xor 16/32
    // sums the wave's 4 rows picking exactly one lane per row -> NO replication
    // scale (round-3 bug: the extra 1/16 made sums 16x too small).
#pragma unroll
    for (int s = 0; s < NS; ++s) {
        float v = ys[s];
        float v2 = ys[s] * ys[s];
        v += __shfl_xor(v, 16);  v2 += __shfl_xor(v2, 16);
        v += __shfl_xor(v, 32);  v2 += __shfl_xor(v2, 32);
        if ((t & 63) == 0) {
            atomicAdd(&sAcc[s], v);
            atomicAdd(&sAcc[NS + s], v2);
        }
    }
    __syncthreads();
    if (t < 2 * NS) {
        const int k = (int)(blockIdx.x & 7);                 // stripe across 8 cache lines
        const int idx = k * 64 + (t < NS ? t : t + 22);      // [k*64+s] / [k*64+32+s]
        atomicAdd(&sums[idx], sAcc[t]);
    }
}

// ---------------- BN finalize ----------------
__global__ __launch_bounds__(256) void gga_bn(
    float* __restrict__ out, const float* __restrict__ sums,
    const float* __restrict__ gamma, const float* __restrict__ beta)
{
    const int idx = blockIdx.x * 256 + threadIdx.x;
    const int s = idx % NS;
    float sm = 0.f, sq = 0.f;
#pragma unroll
    for (int k = 0; k < 8; ++k) {
        sm += sums[k * 64 + s];
        sq += sums[k * 64 + 32 + s];
    }
    const float mu = sm * (1.f / NROWS);
    float var = sq * (1.f / NROWS) - mu * mu;
    var = fmaxf(var, 0.f);
    const float r = rsqrtf(var + BN_EPS);
    const float sc = gamma[s] * r;
    const float sh = beta[s] - mu * sc;
    out[idx] = out[idx] * sc + sh;
}

extern "C" void kernel_launch(void* const* d_in, const int* in_sizes, int n_in,
                              void* d_out, int out_size, void* d_ws, size_t ws_size,
                              hipStream_t stream) {
    const int*   x         = (const int*)d_in[0];
    const float* emb       = (const float*)d_in[1];
    const float* gene_att  = (const float*)d_in[2];
    const float* chrom_att = (const float*)d_in[3];
    const float* W         = (const float*)d_in[4];
    const float* b         = (const float*)d_in[5];
    const float* bn_gamma  = (const float*)d_in[6];
    const float* bn_beta   = (const float*)d_in[7];

    float* y    = (float*)d_out;
    float* sums = (float*)d_ws;

    hipMemsetAsync(d_ws, 0, 2048, stream);   // zero 8-stripe BN accumulators

    if (ws_size >= (size_t)WS_NEED) {
        unsigned* xp  = (unsigned*)((char*)d_ws + WS_XP);
        float*    eLg = (float*)((char*)d_ws + WS_EL);
        float*    WTg = (float*)((char*)d_ws + WS_WT);
        gga_prep<<<NROWS / 32, 256, 0, stream>>>(x, emb, gene_att, W, xp, eLg, WTg);
        gga_main<true><<<NROWS / RPB, BLOCK_A, 0, stream>>>(
            x, xp, emb, gene_att, chrom_att, W, b, eLg, WTg, y, sums);
    } else {
        gga_main<false><<<NROWS / RPB, BLOCK_A, 0, stream>>>(
            x, nullptr, emb, gene_att, chrom_att, W, b, nullptr, nullptr, y, sums);
    }
    gga_bn<<<(NROWS * NS) / 256, 256, 0, stream>>>(y, sums, bn_gamma, bn_beta);
}

// Round 5
// 26.523 us; speedup vs baseline: 1.2475x; 1.2475x over previous
//
#include <hip/hip_runtime.h>
#include <hip/hip_fp16.h>

#define NROWS 16384
#define NG 100
#define NC 10
#define NH 32
#define NS 10
#define GPC 10
#define SLOPE 0.2f
#define BN_EPS 1e-5f

#define EPADH 36           // halfs per LDS emb row (72B stride spreads rows across banks)
#define RPB 32             // rows per block
#define BLOCK_A 512        // 32 rows * 16 lanes/row
#define NB (NROWS / RPB)   // 512 blocks

// d_ws: P[2*NS][NB] floats = 40960 B of per-block BN partials (every slot
// rewritten every launch -> no zeroing, no atomics, replay-deterministic)

template<bool SLOTS>
__global__ __launch_bounds__(BLOCK_A, 4) void gga_main(
    const int* __restrict__ x, const float* __restrict__ emb,
    const float* __restrict__ gene_att, const float* __restrict__ chrom_att,
    const float* __restrict__ W, const float* __restrict__ b,
    float* __restrict__ y, float* __restrict__ P)
{
    __shared__ __half embL[300 * EPADH];   // 21.6 KB
    __shared__ float eL[300];
    __shared__ float WTL[NS * NH];
    __shared__ float bL[NS];
    __shared__ unsigned xpL[RPB * 8];      // packed trits, 8 words/row
    __shared__ float sAcc[2 * NS];

    const int t = threadIdx.x;
    const int n0 = blockIdx.x * RPB;

    // ---- block setup (all independent, one barrier) ----
    // stage emb f32 -> f16 LDS
    for (int i = t; i < 2400; i += BLOCK_A) {
        float4 v = reinterpret_cast<const float4*>(emb)[i];
        int f = i << 2;
        int row = f >> 5, h = f & 31;
        __half2 lo = __floats2half2_rn(v.x, v.y);
        __half2 hi = __floats2half2_rn(v.z, v.w);
        uint2 u;
        u.x = __builtin_bit_cast(unsigned, lo);
        u.y = __builtin_bit_cast(unsigned, hi);
        *reinterpret_cast<uint2*>(&embL[row * EPADH + h]) = u;
    }
    // W^T
    for (int i = t; i < NH * NS; i += BLOCK_A) {
        int s = i >> 5, h = i & 31;
        WTL[i] = W[h * NS + s];
    }
    if (t < NS) bL[t] = b[t];
    if (t < 2 * NS) sAcc[t] = 0.f;
    // e-table from GLOBAL f32 emb (full precision): 300 dot-32
    if (t < 300) {
        const int g = t / 3;
        const float* ga = gene_att + (g / GPC) * NH;
        const float* e = emb + t * NH;
        float s = 0.f;
#pragma unroll
        for (int k = 0; k < NH; k += 4) {
            float4 ev = *reinterpret_cast<const float4*>(e + k);
            float4 gv = *reinterpret_cast<const float4*>(ga + k);
            s = fmaf(gv.x, ev.x, s); s = fmaf(gv.y, ev.y, s);
            s = fmaf(gv.z, ev.z, s); s = fmaf(gv.w, ev.w, s);
        }
        const float lk = s > 0.f ? s : SLOPE * s;
        eL[t] = (s != 0.f) ? __expf(lk) : 0.f;
    }
    // cooperative x pack: (row, word) pairs; word w holds trits 16w..16w+15
    if (t < 256) {
        const int r = t >> 3, w = t & 7;
        unsigned pw = 0u;
        if (w < 7) {
            const int4* p = reinterpret_cast<const int4*>(x + (n0 + r) * NG + w * 16);
            const int nv = (w < 6) ? 4 : 1;   // word 6: trits 96..99 only
#pragma unroll
            for (int i = 0; i < 4; ++i) {
                if (i < nv) {
                    int4 v = p[i];
                    pw |= ((unsigned)v.x & 3u) << (i * 8 + 0);
                    pw |= ((unsigned)v.y & 3u) << (i * 8 + 2);
                    pw |= ((unsigned)v.z & 3u) << (i * 8 + 4);
                    pw |= ((unsigned)v.w & 3u) << (i * 8 + 6);
                }
            }
        }
        xpL[r * 8 + w] = pw;
    }
    __syncthreads();

    // ---- per-row work: 16 lanes/row, lane o owns h components 2o,2o+1 ----
    const int lr = t >> 4;
    const int o = t & 15;
    const int n = n0 + lr;

    const float2 ca = reinterpret_cast<const float2*>(chrom_att)[o];

    const uint4 pa = *reinterpret_cast<const uint4*>(&xpL[lr * 8]);
    const uint4 pb = *reinterpret_cast<const uint4*>(&xpL[lr * 8 + 4]);
    const unsigned pk[8] = {pa.x, pa.y, pa.z, pa.w, pb.x, pb.y, pb.z, pb.w};

    float2 num = {0.f, 0.f};
    float den = 0.f;

#pragma unroll
    for (int c = 0; c < NC; ++c) {
        float e[GPC];
        float2 hf[GPC];
#pragma unroll
        for (int gp = 0; gp < GPC; ++gp) {
            const int g = c * GPC + gp;
            const unsigned xg = (pk[g >> 4] >> ((g & 15) * 2)) & 3u;
            const int r3 = g * 3 + (int)xg;
            e[gp] = eL[r3];                                   // 16-lane broadcast
            __half2 hh = *reinterpret_cast<const __half2*>(&embL[r3 * EPADH + o * 2]);
            hf[gp] = __half22float2(hh);
        }
        float suma = 0.f;
#pragma unroll
        for (int gp = 0; gp < GPC; ++gp) suma += e[gp];
        const float inv = 1.f / fmaxf(suma, 1e-10f);

        float2 ch = {0.f, 0.f};
#pragma unroll
        for (int gp = 0; gp < GPC; ++gp) {
            ch.x = fmaf(e[gp], hf[gp].x, ch.x);
            ch.y = fmaf(e[gp], hf[gp].y, ch.y);
        }
        ch.x = fmaxf(ch.x, 0.f);   // ReLU commutes with positive 1/suma scale
        ch.y = fmaxf(ch.y, 0.f);

        float pc = ch.x * ca.x + ch.y * ca.y;
        pc += __shfl_xor(pc, 1);
        pc += __shfl_xor(pc, 2);
        pc += __shfl_xor(pc, 4);
        pc += __shfl_xor(pc, 8);
        pc *= inv;                                            // catt[n][c]
        const float lc = pc > 0.f ? pc : SLOPE * pc;
        const float ec = __expf(lc);
        const float w = ec * inv;

        num.x = fmaf(w, ch.x, num.x);
        num.y = fmaf(w, ch.y, num.y);
        den += ec;
    }

    const float invd = 1.f / den;
    const float g0 = fmaxf(num.x * invd, 0.f);
    const float g1 = fmaxf(num.y * invd, 0.f);

    float ys[NS];
#pragma unroll
    for (int s = 0; s < NS; ++s) {
        const float2 wv = *reinterpret_cast<const float2*>(&WTL[s * NH + o * 2]);
        float p = g0 * wv.x + g1 * wv.y;
        p += __shfl_xor(p, 1);
        p += __shfl_xor(p, 2);
        p += __shfl_xor(p, 4);
        p += __shfl_xor(p, 8);
        ys[s] = p + bL[s];
    }

    if (o == 0) {
        float2* yp = reinterpret_cast<float2*>(y + n * NS);   // 8B aligned
#pragma unroll
        for (int s2 = 0; s2 < 5; ++s2) yp[s2] = make_float2(ys[2 * s2], ys[2 * s2 + 1]);
    }

    // BN partials: ys uniform across a row's 16 o-lanes; xor16/32 sums the
    // wave's 4 rows once each (no replication scale).
#pragma unroll
    for (int s = 0; s < NS; ++s) {
        float v = ys[s];
        float v2 = ys[s] * ys[s];
        v += __shfl_xor(v, 16);  v2 += __shfl_xor(v2, 16);
        v += __shfl_xor(v, 32);  v2 += __shfl_xor(v2, 32);
        if ((t & 63) == 0) {
            atomicAdd(&sAcc[s], v);
            atomicAdd(&sAcc[NS + s], v2);
        }
    }
    __syncthreads();
    if (t < 2 * NS) {
        if (SLOTS) P[t * NB + blockIdx.x] = sAcc[t];   // plain store, no zeroing needed
        else       atomicAdd(&P[t], sAcc[t]);          // fallback (tiny ws)
    }
}

// ---------------- BN finalize: reduce slots + apply, float4 I/O ----------------
template<bool SLOTS>
__global__ __launch_bounds__(256) void gga_bn(
    float* __restrict__ out, const float* __restrict__ P,
    const float* __restrict__ gamma, const float* __restrict__ beta)
{
    __shared__ float red[2 * NS * 8];
    __shared__ float scL[NS], shL[NS];
    const int t = threadIdx.x;

    if (SLOTS) {
        if (t < 2 * NS * 8) {                      // 160 reducer threads
            const int k = t >> 3, c = t & 7;
            const float4* p4 = reinterpret_cast<const float4*>(P + k * NB + c * 64);
            float s = 0.f;
#pragma unroll
            for (int i = 0; i < 16; ++i) {
                float4 v = p4[i];
                s += v.x + v.y + v.z + v.w;
            }
            red[t] = s;
        }
        __syncthreads();
    }
    if (t < NS) {
        float sm, sq;
        if (SLOTS) {
            sm = 0.f; sq = 0.f;
#pragma unroll
            for (int c = 0; c < 8; ++c) {
                sm += red[t * 8 + c];
                sq += red[(NS + t) * 8 + c];
            }
        } else {
            sm = P[t]; sq = P[NS + t];
        }
        const float mu = sm * (1.f / NROWS);
        float var = sq * (1.f / NROWS) - mu * mu;
        var = fmaxf(var, 0.f);
        const float r = rsqrtf(var + BN_EPS);
        scL[t] = gamma[t] * r;
        shL[t] = beta[t] - mu * scL[t];
    }
    __syncthreads();

    const int i4 = (blockIdx.x * 256 + t) * 4;
    float4 v = *reinterpret_cast<const float4*>(out + i4);
    const int s0 = i4 % NS;
    const int s1 = (s0 + 1) % NS, s2 = (s0 + 2) % NS, s3 = (s0 + 3) % NS;
    v.x = fmaf(v.x, scL[s0], shL[s0]);
    v.y = fmaf(v.y, scL[s1], shL[s1]);
    v.z = fmaf(v.z, scL[s2], shL[s2]);
    v.w = fmaf(v.w, scL[s3], shL[s3]);
    *reinterpret_cast<float4*>(out + i4) = v;
}

extern "C" void kernel_launch(void* const* d_in, const int* in_sizes, int n_in,
                              void* d_out, int out_size, void* d_ws, size_t ws_size,
                              hipStream_t stream) {
    const int*   x         = (const int*)d_in[0];
    const float* emb       = (const float*)d_in[1];
    const float* gene_att  = (const float*)d_in[2];
    const float* chrom_att = (const float*)d_in[3];
    const float* W         = (const float*)d_in[4];
    const float* b         = (const float*)d_in[5];
    const float* bn_gamma  = (const float*)d_in[6];
    const float* bn_beta   = (const float*)d_in[7];

    float* y = (float*)d_out;
    float* P = (float*)d_ws;

    if (ws_size >= (size_t)(2 * NS * NB * sizeof(float))) {
        gga_main<true><<<NB, BLOCK_A, 0, stream>>>(
            x, emb, gene_att, chrom_att, W, b, y, P);
        gga_bn<true><<<(NROWS * NS) / (256 * 4), 256, 0, stream>>>(
            y, P, bn_gamma, bn_beta);
    } else {
        hipMemsetAsync(P, 0, 2 * NS * sizeof(float), stream);
        gga_main<false><<<NB, BLOCK_A, 0, stream>>>(
            x, emb, gene_att, chrom_att, W, b, y, P);
        gga_bn<false><<<(NROWS * NS) / (256 * 4), 256, 0, stream>>>(
            y, P, bn_gamma, bn_beta);
    }
}